// Round 4
// baseline (869.769 us; speedup 1.0000x reference)
//
#include <hip/hip_runtime.h>
#include <hip/hip_bf16.h>

typedef unsigned short u16;
typedef unsigned int u32x4 __attribute__((ext_vector_type(4)));
typedef unsigned short us4 __attribute__((ext_vector_type(4)));
typedef __bf16 bf16x8 __attribute__((ext_vector_type(8)));
typedef float f32x4 __attribute__((ext_vector_type(4)));

__device__ __forceinline__ float b2f(u16 u) {
  union { unsigned int i; float f; } v; v.i = ((unsigned int)u) << 16; return v.f;
}
__device__ __forceinline__ u16 f2b(float f) {
  unsigned int x = __builtin_bit_cast(unsigned int, f);
  unsigned int r = (x + 0x7fffu + ((x >> 16) & 1u)) >> 16;
  return (u16)r;
}

// async global->LDS, 16B per lane; LDS dest is wave-uniform base, HW writes
// lane i's 16B at base + i*16 (m104/m108). Global source is per-lane.
__device__ __forceinline__ void stage16(const u16* g, u16* l) {
  __builtin_amdgcn_global_load_lds((const __attribute__((address_space(1))) void*)g,
                                   (__attribute__((address_space(3))) void*)l,
                                   16, 0, 0);
}

// ---------------- fp32 -> bf16 bulk convert (h_prev only) ------------------
__global__ void cvt_k(const float* __restrict__ in, u16* __restrict__ out, long n) {
  long i = ((long)blockIdx.x * 256 + threadIdx.x) * 4;
  if (i + 3 < n) {
    float4 v = *(const float4*)(in + i);
    out[i] = f2b(v.x); out[i+1] = f2b(v.y); out[i+2] = f2b(v.z); out[i+3] = f2b(v.w);
  } else {
    for (long k = i; k < n; ++k) out[k] = f2b(in[k]);
  }
}

// ---- generic transpose + fp32->bf16: in [R,C] f32 -> out [C,ldo] bf16
// rows R..ldo-1 of output zero-filled (down-proj K padding 2730->2752).
__global__ void transpose_k(const float* __restrict__ in, u16* __restrict__ out,
                            int R, int C, int ldo) {
  __shared__ float t[32][33];
  int c0 = blockIdx.x * 32, r0 = blockIdx.y * 32;
  for (int i = threadIdx.y; i < 32; i += 8) {
    int r = r0 + i, c = c0 + threadIdx.x;
    t[i][threadIdx.x] = (r < R && c < C) ? in[(long)r * C + c] : 0.f;
  }
  __syncthreads();
  for (int i = threadIdx.y; i < 32; i += 8) {
    int c = c0 + i, r = r0 + threadIdx.x;
    if (c < C && r < ldo) out[(long)c * ldo + r] = f2b(t[threadIdx.x][i]);
  }
}

// ---- 6 gate-weight transposes in one launch: each [8][256][256] f32,
// interleaved into zoW/zoR/irfW slabs ([8][512][256] bf16).
__global__ void transpose6_k(const float* __restrict__ Wz, const float* __restrict__ Wo,
                             const float* __restrict__ Rz, const float* __restrict__ Ro,
                             const float* __restrict__ Ri, const float* __restrict__ Rf,
                             u16* __restrict__ zoW, u16* __restrict__ zoR,
                             u16* __restrict__ irfW) {
  __shared__ float t[32][33];
  int zz = blockIdx.z; int wsel = zz >> 3, h = zz & 7;
  const float* in; u16* outp;
  switch (wsel) {
    case 0: in = Wz; outp = zoW;          break;
    case 1: in = Wo; outp = zoW + 65536;  break;
    case 2: in = Rz; outp = zoR;          break;
    case 3: in = Ro; outp = zoR + 65536;  break;
    case 4: in = Ri; outp = irfW;         break;
    default: in = Rf; outp = irfW + 65536; break;
  }
  in += (long)h * 65536; outp += (long)h * 131072;
  int c0 = blockIdx.x * 32, r0 = blockIdx.y * 32;
  for (int i = threadIdx.y; i < 32; i += 8)
    t[i][threadIdx.x] = in[(long)(r0 + i) * 256 + c0 + threadIdx.x];
  __syncthreads();
  for (int i = threadIdx.y; i < 32; i += 8)
    outp[(long)(c0 + i) * 256 + r0 + threadIdx.x] = f2b(t[threadIdx.x][i]);
}

// ---- upL/upR transposes in one launch: [2048,2730] f32 -> [2730][2048] bf16
__global__ void transpose_up_k(const float* __restrict__ L, const float* __restrict__ R,
                               u16* __restrict__ out) {
  __shared__ float t[32][33];
  const float* in = blockIdx.z ? R : L;
  u16* o = out + (long)blockIdx.z * 2730 * 2048;
  int c0 = blockIdx.x * 32, r0 = blockIdx.y * 32;
  for (int i = threadIdx.y; i < 32; i += 8) {
    int r = r0 + i, c = c0 + threadIdx.x;
    t[i][threadIdx.x] = (c < 2730) ? in[(long)r * 2730 + c] : 0.f;
  }
  __syncthreads();
  for (int i = threadIdx.y; i < 32; i += 8) {
    int c = c0 + i, r = r0 + threadIdx.x;
    if (c < 2730) o[(long)c * 2048 + r] = f2b(t[threadIdx.x][i]);
  }
}

// ---- column sums of both block-diag weights [8,256,256] in one launch -----
// grid (32, 2): y selects Wi/Wf; x = (head<<2)|colquad; 256 thr = 4 rowgrp x 64 col
__global__ void colsum2_k(const float* __restrict__ Wi, const float* __restrict__ Wf,
                          float* __restrict__ csi, float* __restrict__ csf) {
  const float* W = blockIdx.y ? Wf : Wi;
  float* outp = blockIdx.y ? csf : csi;
  int bb = blockIdx.x; int h = bb >> 2, cq = bb & 3;
  int t = threadIdx.x;
  int col = cq * 64 + (t & 63);
  int rg = t >> 6;
  const float* p = W + (long)h * 65536 + col;
  float s = 0.f;
  for (int r = rg * 64; r < rg * 64 + 64; ++r) s += p[(long)r * 256];
  __shared__ float red[4][64];
  red[rg][t & 63] = s;
  __syncthreads();
  if (t < 64) outp[h * 256 + cq * 64 + t] = red[0][t] + red[1][t] + red[2][t] + red[3][t];
}

// ---- LayerNorm + conv scalar + silu -> xc[B]; also emits bf16(x) -> xb ----
__global__ void ln_conv_k(const float* __restrict__ x, const float* __restrict__ g,
                          const float* __restrict__ bb, const float* __restrict__ ck,
                          const float* __restrict__ cb, float* __restrict__ xc,
                          u16* __restrict__ xb) {
  __shared__ float s1[4], s2[4];
  int b = blockIdx.x, tid = threadIdx.x;
  const float* xr = x + (long)b * 2048;
  u16* xbr = xb + (long)b * 2048;
  float v[8], sum = 0.f, sq = 0.f;
  #pragma unroll
  for (int i = 0; i < 8; ++i) {
    float f = xr[tid + i * 256];
    v[i] = f; sum += f; sq += f * f;
    xbr[tid + i * 256] = f2b(f);
  }
  #pragma unroll
  for (int off = 32; off; off >>= 1) {
    sum += __shfl_down(sum, off, 64);
    sq  += __shfl_down(sq,  off, 64);
  }
  int lane = tid & 63, wv = tid >> 6;
  if (!lane) { s1[wv] = sum; s2[wv] = sq; }
  __syncthreads();
  float tsum = s1[0] + s1[1] + s1[2] + s1[3];
  float tsq  = s2[0] + s2[1] + s2[2] + s2[3];
  float m = tsum * (1.f / 2048.f);
  float var = tsq * (1.f / 2048.f) - m * m;
  float rstd = rsqrtf(var + 1e-3f);
  float dot = 0.f;
  #pragma unroll
  for (int i = 0; i < 8; ++i) {
    int d = tid + i * 256;
    float xn = (v[i] - m) * rstd * g[d] + bb[d];
    dot += xn * ck[3 * 2048 + d];
  }
  #pragma unroll
  for (int off = 32; off; off >>= 1) dot += __shfl_down(dot, off, 64);
  __syncthreads();
  if (!lane) s1[wv] = dot;
  __syncthreads();
  if (tid == 0) {
    float s = s1[0] + s1[1] + s1[2] + s1[3] + cb[0];
    xc[b] = s / (1.f + expf(-s));  // silu
  }
}

// ---------------- MFMA GEMM: C = A1*B1t^T + A2*B2t^T (+bias)(+res) ---------
// m97 structure: 128x128 tile, BK=32, linear LDS [128][32], global_load_lds
// width 16, XCD-aware block swizzle (T1). K1 and K1+K2 multiples of 32.
// Epilogue col-split: col >= nsplit gets element offset += off2.
template<bool F32OUT>
__global__ __launch_bounds__(256) void gemm_bt(
    const u16* __restrict__ A1, long lda1, long sA1,
    const u16* __restrict__ Bt1, long ldb1, long sB1,
    const u16* __restrict__ A2, long lda2, long sA2,
    const u16* __restrict__ Bt2, long ldb2, long sB2,
    int K1, int K2,
    const float* __restrict__ bias,
    const float* __restrict__ res, long ldres,
    void* __restrict__ Cv, long ldc, long sC,
    int M, int N, int nsplit, long off2)
{
  __shared__ u16 As[128][32];
  __shared__ u16 Bs[128][32];
  const int bz = blockIdx.z;
  A1 += (long)bz * sA1; Bt1 += (long)bz * sB1;
  if (A2) { A2 += (long)bz * sA2; Bt2 += (long)bz * sB2; }
  // XCD-aware swizzle: contiguous chunks of linear block id per XCD (T1/m157).
  int gx = gridDim.x;
  int lin = blockIdx.y * gx + blockIdx.x;
  int nwg = gx * gridDim.y;
  if ((nwg & 7) == 0) {
    int cpx = nwg >> 3;
    lin = (lin & 7) * cpx + (lin >> 3);
  }
  const int m0 = (lin / gx) * 128, n0 = (lin % gx) * 128;
  const int tid = threadIdx.x;
  const int w = tid >> 6, lane = tid & 63;
  const int lr = lane & 15, quad = lane >> 4;
  const int wrow = (w & 1) * 64, wcol = (w >> 1) * 64;
  // staging: wave w, chunk c -> 16 rows at (w*2+c)*16; lane l covers row
  // +l/4, elems [(l&3)*8,+8) == LDS base + l*16B (linear).
  const int srow = lane >> 2;
  const int scol = (lane & 3) * 8;
  f32x4 acc[4][4] = {};
  const int KT = K1 + K2;
  for (int kk = 0; kk < KT; kk += 32) {
    const u16 *PA, *PB; long lA, lB; int ko;
    if (kk < K1) { PA = A1; lA = lda1; PB = Bt1; lB = ldb1; ko = kk; }
    else         { PA = A2; lA = lda2; PB = Bt2; lB = ldb2; ko = kk - K1; }
    #pragma unroll
    for (int c = 0; c < 2; ++c) {
      const int r0 = (w * 2 + c) * 16;
      long ar = m0 + r0 + srow; if (ar > (long)M - 1) ar = M - 1;
      long br = n0 + r0 + srow; if (br > (long)N - 1) br = N - 1;  // OOB cols never stored
      stage16(PA + ar * lA + ko + scol, &As[r0][0]);
      stage16(PB + br * lB + ko + scol, &Bs[r0][0]);
    }
    asm volatile("s_waitcnt vmcnt(0)" ::: "memory");
    __syncthreads();
    bf16x8 af[4], bfr[4];
    #pragma unroll
    for (int i = 0; i < 4; ++i)
      af[i] = __builtin_bit_cast(bf16x8, *(const u32x4*)&As[wrow + i * 16 + lr][quad * 8]);
    #pragma unroll
    for (int j = 0; j < 4; ++j)
      bfr[j] = __builtin_bit_cast(bf16x8, *(const u32x4*)&Bs[wcol + j * 16 + lr][quad * 8]);
    #pragma unroll
    for (int i = 0; i < 4; ++i)
      #pragma unroll
      for (int j = 0; j < 4; ++j)
        acc[i][j] = __builtin_amdgcn_mfma_f32_16x16x32_bf16(af[i], bfr[j], acc[i][j], 0, 0, 0);
    __syncthreads();
  }
  #pragma unroll
  for (int i = 0; i < 4; ++i) {
    #pragma unroll
    for (int r = 0; r < 4; ++r) {
      int row = m0 + wrow + i * 16 + quad * 4 + r;
      if (row >= M) continue;
      #pragma unroll
      for (int j = 0; j < 4; ++j) {
        int col = n0 + wcol + j * 16 + lr;
        if (col >= N) continue;
        float v = acc[i][j][r];
        if (bias) v += bias[col];
        if (res)  v += res[(long)row * ldres + col];
        long e = (long)bz * sC + (long)row * ldc + col;
        if (col >= nsplit) e += off2;
        if (F32OUT) ((float*)Cv)[e] = v;
        else        ((u16*)Cv)[e] = f2b(v);
      }
    }
  }
}

// ---- fused gate math + GroupNorm: block = one (b, group) of 256 elems,
// 64 threads x 4-wide. Writes h/c/n/m (fp32 outputs) + onorm (bf16).
__global__ void gates_gn_k(
    const u16* __restrict__ zpre, const u16* __restrict__ opre,
    const u16* __restrict__ ri,   const u16* __restrict__ rf,
    const float* __restrict__ xc, const float* __restrict__ csi, const float* __restrict__ csf,
    const float* __restrict__ Wz_b, const float* __restrict__ Rz_b,
    const float* __restrict__ Wi_b, const float* __restrict__ Ri_b,
    const float* __restrict__ Wf_b, const float* __restrict__ Rf_b,
    const float* __restrict__ Wo_b, const float* __restrict__ Ro_b,
    const float* __restrict__ c_prev, const float* __restrict__ n_prev,
    const float* __restrict__ m_prev,
    const float* __restrict__ gn_g, const float* __restrict__ gn_b,
    float* __restrict__ h_out, float* __restrict__ c_out,
    float* __restrict__ n_out, float* __restrict__ m_out,
    u16* __restrict__ onorm)
{
  int t = threadIdx.x;                       // 64 threads
  long base = (long)blockIdx.x * 256 + t * 4;
  int j = (int)(base & 2047);
  long b = base >> 11;
  us4 z4 = *(const us4*)(zpre + base);
  us4 o4 = *(const us4*)(opre + base);
  us4 i4 = *(const us4*)(ri + base);
  us4 f4 = *(const us4*)(rf + base);
  f32x4 cp = *(const f32x4*)(c_prev + base);
  f32x4 np = *(const f32x4*)(n_prev + base);
  f32x4 mp = *(const f32x4*)(m_prev + base);
  float xcb = xc[b];
  float ht[4]; f32x4 ho, co, no, mo;
  float sum = 0.f, sq = 0.f;
  #pragma unroll
  for (int e = 0; e < 4; ++e) {
    int jj = j + e;
    float zp = b2f(z4[e]) + Wz_b[jj] + Rz_b[jj];
    float op = b2f(o4[e]) + Wo_b[jj] + Ro_b[jj];
    float it = xcb * csi[jj] + Wi_b[jj] + b2f(i4[e]) + Ri_b[jj];
    float ft = xcb * csf[jj] + Wf_b[jj] + b2f(f4[e]) + Rf_b[jj];
    float z = tanhf(zp);
    float o = 1.f / (1.f + expf(-op));
    float mt = fmaxf(ft + mp[e], it);
    float ii = expf(it - mt), ff = expf(ft + mp[e] - mt);
    float ct = ff * cp[e] + ii * z;
    float nt = ff * np[e] + ii;
    float h = o * ct / nt;
    ht[e] = h; ho[e] = h; co[e] = ct; no[e] = nt; mo[e] = mt;
    sum += h; sq += h * h;
  }
  *(f32x4*)(h_out + base) = ho;
  *(f32x4*)(c_out + base) = co;
  *(f32x4*)(n_out + base) = no;
  *(f32x4*)(m_out + base) = mo;
  #pragma unroll
  for (int off = 32; off; off >>= 1) {
    sum += __shfl_down(sum, off, 64);
    sq  += __shfl_down(sq,  off, 64);
  }
  sum = __shfl(sum, 0, 64); sq = __shfl(sq, 0, 64);
  float m = sum * (1.f / 256.f);
  float var = sq * (1.f / 256.f) - m * m;
  float rstd = rsqrtf(var + 1e-3f);
  us4 og;
  #pragma unroll
  for (int e = 0; e < 4; ++e)
    og[e] = f2b((ht[e] - m) * rstd * gn_g[j + e] + gn_b[j + e]);
  *(us4*)(onorm + base) = og;
}

// -------- GLU combine on fused buf [4096][5504]: left=cols 0..2729,
// right=cols 2752..; act = (L+lb)*gelu_exact(R+rb); zero-fill 2730..2751.
__global__ void combine_k(u16* __restrict__ buf,
                          const float* __restrict__ lb, const float* __restrict__ rb) {
  int i4 = blockIdx.x * 256 + threadIdx.x;   // 0..687 (x4 cols)
  if (i4 >= 688) return;
  int col = i4 * 4;
  long base = (long)blockIdx.y * 5504 + col;
  us4 l4 = *(const us4*)(buf + base);
  us4 r4 = *(const us4*)(buf + base + 2752);
  us4 a;
  #pragma unroll
  for (int e = 0; e < 4; ++e) {
    int c = col + e;
    if (c >= 2730) { a[e] = 0; continue; }
    float l = b2f(l4[e]) + lb[c];
    float r = b2f(r4[e]) + rb[c];
    float gel = 0.5f * r * (1.f + erff(r * 0.70710678118654752f));
    a[e] = f2b(l * gel);
  }
  *(us4*)(buf + base) = a;
}

extern "C" void kernel_launch(void* const* d_in, const int* in_sizes, int n_in,
                              void* d_out, int out_size, void* d_ws, size_t ws_size,
                              hipStream_t stream)
{
  const float* x      = (const float*)d_in[0];
  const float* h_prev = (const float*)d_in[1];
  const float* c_prev = (const float*)d_in[2];
  const float* n_prev = (const float*)d_in[3];
  const float* m_prev = (const float*)d_in[4];
  const float* ln_g   = (const float*)d_in[5];
  const float* ln_b   = (const float*)d_in[6];
  const float* conv_k = (const float*)d_in[7];
  const float* conv_b = (const float*)d_in[8];
  const float* Wz_w = (const float*)d_in[9];  const float* Wz_b = (const float*)d_in[10];
  const float* Wi_w = (const float*)d_in[11]; const float* Wi_b = (const float*)d_in[12];
  const float* Wf_w = (const float*)d_in[13]; const float* Wf_b = (const float*)d_in[14];
  const float* Wo_w = (const float*)d_in[15]; const float* Wo_b = (const float*)d_in[16];
  const float* Rz_w = (const float*)d_in[17]; const float* Rz_b = (const float*)d_in[18];
  const float* Ri_w = (const float*)d_in[19]; const float* Ri_b = (const float*)d_in[20];
  const float* Rf_w = (const float*)d_in[21]; const float* Rf_b = (const float*)d_in[22];
  const float* Ro_w = (const float*)d_in[23]; const float* Ro_b = (const float*)d_in[24];
  const float* gn_g = (const float*)d_in[25]; const float* gn_b = (const float*)d_in[26];
  const float* upL_w = (const float*)d_in[27]; const float* upL_b = (const float*)d_in[28];
  const float* upR_w = (const float*)d_in[29]; const float* upR_b = (const float*)d_in[30];
  const float* down_w = (const float*)d_in[31]; const float* down_b = (const float*)d_in[32];

  char* ws = (char*)d_ws;
  u16* zoW   = (u16*)(ws + 0);                // [8][512][256]  rows: Wz^T | Wo^T
  u16* zoR   = (u16*)(ws + 2097152);          // [8][512][256]  rows: Rz^T | Ro^T
  u16* irfW  = (u16*)(ws + 4194304);          // [8][512][256]  rows: Ri^T | Rf^T
  u16* upLT  = (u16*)(ws + 6291456);          // [5460][2048]  (upL^T | upR^T)
  u16* downT = (u16*)(ws + 28655616);         // [2048][2752]  rows 2730.. zero
  float* csi = (float*)(ws + 39945216);
  float* csf = (float*)(ws + 39953408);
  float* xc  = (float*)(ws + 39961600);
  u16* zpre  = (u16*)(ws + 39980032);         // [4096][2048] bf16
  u16* opre  = (u16*)(ws + 56757248);
  u16* ri    = (u16*)(ws + 73534464);
  u16* rf    = (u16*)(ws + 90311680);
  u16* xb    = (u16*)(ws + 107088896);        // bf16(x)
  u16* hb    = (u16*)(ws + 123866112);        // bf16(h_prev)
  u16* onorm = xb;                            // alias: xb free after gate GEMMs
  u16* updub = zpre;                          // [4096][5504]: L | pad | R

  float* out   = (float*)d_out;
  float* final_o = out;
  float* hout  = out + 8388608;
  float* cout  = out + 16777216;
  float* nout  = out + 25165824;
  float* mout  = out + 33554432;

  const long GATE_OFF2 = 8388608 - 256;
  const int  NOSPLIT = 1 << 30;

  dim3 tb(32, 8);
  cvt_k<<<8192, 256, 0, stream>>>(h_prev, hb, 8388608);
  ln_conv_k<<<4096, 256, 0, stream>>>(x, ln_g, ln_b, conv_k, conv_b, xc, xb);
  transpose6_k<<<dim3(8, 8, 48), tb, 0, stream>>>(Wz_w, Wo_w, Rz_w, Ro_w, Ri_w, Rf_w,
                                                  zoW, zoR, irfW);
  transpose_up_k<<<dim3(86, 64, 2), tb, 0, stream>>>(upL_w, upR_w, upLT);
  transpose_k<<<dim3(64, 86, 1), tb, 0, stream>>>(down_w, downT, 2730, 2048, 2752);
  colsum2_k<<<dim3(32, 2), 256, 0, stream>>>(Wi_w, Wf_w, csi, csf);
  // fused z+o gate GEMM: [xb|hb] @ [zoW;zoR]^T per head -> zpre / opre
  gemm_bt<false><<<dim3(4, 32, 8), 256, 0, stream>>>(
      xb, 2048, 256, zoW, 256, 131072, hb, 2048, 256, zoR, 256, 131072,
      256, 256, nullptr, nullptr, 0, zpre, 2048, 256, 4096, 512, 256, GATE_OFF2);
  // fused i+f recurrent GEMM: hb @ [Ri;Rf]^T per head -> ri / rf
  gemm_bt<false><<<dim3(4, 32, 8), 256, 0, stream>>>(
      hb, 2048, 256, irfW, 256, 131072, nullptr, 0, 0, nullptr, 0, 0,
      256, 0, nullptr, nullptr, 0, ri, 2048, 256, 4096, 512, 256, GATE_OFF2);
  // fused gate math + GroupNorm
  gates_gn_k<<<32768, 64, 0, stream>>>(zpre, opre, ri, rf, xc, csi, csf,
      Wz_b, Rz_b, Wi_b, Ri_b, Wf_b, Rf_b, Wo_b, Ro_b,
      c_prev, n_prev, m_prev, gn_g, gn_b, hout, cout, nout, mout, onorm);
  // fused up projection: onorm @ [upL|upR]^T, N=5460 -> updub halves
  gemm_bt<false><<<dim3(43, 32, 1), 256, 0, stream>>>(
      onorm, 2048, 0, upLT, 2048, 0, nullptr, 0, 0, nullptr, 0, 0,
      2048, 0, nullptr, nullptr, 0, updub, 5504, 0, 4096, 5460, 2730, 22);
  // GLU combine in place (left half), zero-pads K to 2752
  combine_k<<<dim3(3, 4096), 256, 0, stream>>>(updub, upL_b, upR_b);
  // down projection + bias + residual -> final output (fp32), K=2752
  gemm_bt<true><<<dim3(16, 32, 1), 256, 0, stream>>>(
      updub, 5504, 0, downT, 2752, 0, nullptr, 0, 0, nullptr, 0, 0,
      2752, 0, down_b, x, 2048, final_o, 2048, 0, 4096, 2048, NOSPLIT, 0);
}